// Round 3
// baseline (677.235 us; speedup 1.0000x reference)
//
#include <hip/hip_runtime.h>
#include <stdint.h>

typedef unsigned short u16;
typedef __bf16 bf16_t;
typedef bf16_t bf16x8 __attribute__((ext_vector_type(8)));
typedef float f32x4 __attribute__((ext_vector_type(4)));
typedef float f32x16 __attribute__((ext_vector_type(16)));
typedef u16 u16x4 __attribute__((ext_vector_type(4)));
typedef u16 u16x8 __attribute__((ext_vector_type(8)));
typedef uint32_t u32x4 __attribute__((ext_vector_type(4)));
typedef int i32x2 __attribute__((ext_vector_type(2)));

#define HIDDEN 4096
#define NTOK 2048
#define NQ 32
#define NKV 8
#define HD 128
#define QKV_N 6144

#define AS1 __attribute__((address_space(1)))
#define AS3 __attribute__((address_space(3)))

__device__ __forceinline__ u16 f2bf(float f) {
  union { float f; uint32_t u; } v; v.f = f;
  uint32_t u = v.u;
  return (u16)((u + 0x7fffu + ((u >> 16) & 1u)) >> 16);
}

// ---------------- hidden fp32 -> bf16 ----------------
__global__ void cvt_hidden(const float* __restrict__ src, u16* __restrict__ dst, int n4) {
  int i = blockIdx.x * blockDim.x + threadIdx.x;
  if (i >= n4) return;
  float4 v = ((const float4*)src)[i];
  u16x4 o;
  o[0] = f2bf(v.x); o[1] = f2bf(v.y); o[2] = f2bf(v.z); o[3] = f2bf(v.w);
  ((u16x4*)dst)[i] = o;
}

// ------------- transpose + convert: dst[c][r] = bf16(src[r][c]) -------------
__global__ void transpose_cvt(const float* __restrict__ src, u16* __restrict__ dst,
                              int R, int C) {
  __shared__ float tile[64][65];
  int tx = threadIdx.x & 63;
  int ty = threadIdx.x >> 6;   // 0..3
  int r0 = blockIdx.y * 64, c0 = blockIdx.x * 64;
  for (int i = 0; i < 16; i++) {
    int r = ty + i * 4;
    tile[r][tx] = src[(size_t)(r0 + r) * C + c0 + tx];
  }
  __syncthreads();
  for (int i = 0; i < 16; i++) {
    int c = ty + i * 4;
    dst[(size_t)(c0 + c) * R + r0 + tx] = f2bf(tile[tx][c]);
  }
}

// ================= GEMM 256x256 8-phase v2: C[M][N] = A[M][K] * B[N][K]^T =======
// bf16 in, fp32 out. BK=64, dbuf LDS (128 KiB), 8 waves (2Mx4N), 512 thr.
// v2: ONE-PHASE-LOOKAHEAD ds_reads — phase p issues frags for phase p+1, then runs
// MFMA p immediately (no lgkm wait on critical path; compiler's counted lgkmcnt for
// last-phase loads is ~free). Tile-b quadrant order (01)(00)(10)(11) makes every RD
// collision-free with the same-phase MFMA operands.
// Stage slots: ph1:buf1.A0(tb) ph2:buf1.A1(tb) ph3:buf0.B0(t2) ph4:buf0.B1(t2)
//   ph5:buf0.A0(t2) ph6:buf0.A1(t2) ph7:buf1.B0(t3) ph8:buf1.B1(t3)
// vmcnt(4) gates only at ph4/ph8 (drain exactly the tile about to be read).
#define BARRIER() do { asm volatile("" ::: "memory"); __builtin_amdgcn_s_barrier(); asm volatile("" ::: "memory"); } while (0)
#define WAIT_VM4() asm volatile("s_waitcnt vmcnt(4)" ::: "memory")
#define WAIT_VM0() asm volatile("s_waitcnt vmcnt(0)" ::: "memory")

#define STAGE_A(buf, half, t) do { \
  __builtin_amdgcn_global_load_lds((AS1 void*)(void*)(gA + (size_t)((half) * 128) * K + (t) * 64), \
      (AS3 void*)(void*)(&sA[buf][((half) * 128) * 64 + lds0]), 16, 0, 0); \
  __builtin_amdgcn_global_load_lds((AS1 void*)(void*)(gA + (size_t)((half) * 128 + 64) * K + (t) * 64), \
      (AS3 void*)(void*)(&sA[buf][((half) * 128 + 64) * 64 + lds0]), 16, 0, 0); \
} while (0)

#define STAGE_B(buf, half, t) do { \
  __builtin_amdgcn_global_load_lds((AS1 void*)(void*)(gB + (size_t)((half) * 128) * K + (t) * 64), \
      (AS3 void*)(void*)(&sB[buf][((half) * 128) * 64 + lds0]), 16, 0, 0); \
  __builtin_amdgcn_global_load_lds((AS1 void*)(void*)(gB + (size_t)((half) * 128 + 64) * K + (t) * 64), \
      (AS3 void*)(void*)(&sB[buf][((half) * 128 + 64) * 64 + lds0]), 16, 0, 0); \
} while (0)

#define RD_A(buf, mh, dst) do { \
  _Pragma("unroll") for (int m_ = 0; m_ < 4; m_++) \
  _Pragma("unroll") for (int s_ = 0; s_ < 2; s_++) \
    dst[m_][s_] = *(const bf16x8*)(const void*)(&sA[buf][(wy * 128 + ((mh) * 4 + m_) * 16 + l16) * 64 + ((s_ * 4 + quad) ^ swz) * 8]); \
} while (0)

#define RD_B(buf, nh, dst) do { \
  _Pragma("unroll") for (int n_ = 0; n_ < 2; n_++) \
  _Pragma("unroll") for (int s_ = 0; s_ < 2; s_++) \
    dst[n_][s_] = *(const bf16x8*)(const void*)(&sB[buf][(wx * 64 + ((nh) * 2 + n_) * 16 + l16) * 64 + ((s_ * 4 + quad) ^ swz) * 8]); \
} while (0)

#define MFMA16(mh, nh, a_, b_) do { \
  __builtin_amdgcn_s_setprio(1); \
  _Pragma("unroll") for (int s_ = 0; s_ < 2; s_++) \
  _Pragma("unroll") for (int m_ = 0; m_ < 4; m_++) \
  _Pragma("unroll") for (int n_ = 0; n_ < 2; n_++) \
    acc[(mh) * 4 + m_][(nh) * 2 + n_] = __builtin_amdgcn_mfma_f32_16x16x32_bf16( \
        a_[m_][s_], b_[n_][s_], acc[(mh) * 4 + m_][(nh) * 2 + n_], 0, 0, 0); \
  __builtin_amdgcn_s_setprio(0); \
} while (0)

__global__ __launch_bounds__(512, 2) void gemm256(const u16* __restrict__ A,
                                                  const u16* __restrict__ B,
                                                  float* __restrict__ C,
                                                  int M, int N, int K) {
  __shared__ u16 sA[2][256 * 64];
  __shared__ u16 sB[2][256 * 64];
  const int tid = threadIdx.x;
  const int wave = tid >> 6, lane = tid & 63;
  const int quad = lane >> 4, l16 = lane & 15;
  const int wy = wave >> 2, wx = wave & 3;
  const int row0 = blockIdx.y * 256, col0 = blockIdx.x * 256;
  f32x4 acc[8][4] = {};
  const int srow = tid >> 3, schunk = tid & 7;
  const int gchunk = schunk ^ (srow & 7);
  const u16* gA = A + (size_t)(row0 + srow) * K + gchunk * 8;
  const u16* gB = B + (size_t)(col0 + srow) * K + gchunk * 8;
  const int lds0 = srow * 64 + schunk * 8;
  const int swz = l16 & 7;

  // prologue: tile0 fully (buf0), tile1 B halves (buf1)
  STAGE_B(0, 0, 0); STAGE_B(0, 1, 0); STAGE_A(0, 0, 0); STAGE_A(0, 1, 0);
  STAGE_B(1, 0, 1); STAGE_B(1, 1, 1);
  WAIT_VM4();   // tile0 landed
  BARRIER();

  bf16x8 a0[4][2], a1[4][2], b0[2][2], b1[2][2];
  RD_A(0, 0, a0); RD_B(0, 0, b0);    // frags for ph1

  const int nIter = (K >> 6) >> 1;
  for (int i = 0; i < nIter; i++) {
    const int tb = 2 * i + 1, t2 = 2 * i + 2, t3 = 2 * i + 3;
    const bool more = (i + 1 < nIter);
    // ---- tile a = 2i (buf0), quadrants (00)(01)(11)(10) ----
    // ph1
    STAGE_A(1, 0, tb);
    BARRIER();
    RD_B(0, 1, b1);                  // for ph2
    MFMA16(0, 0, a0, b0);
    BARRIER();
    // ph2
    STAGE_A(1, 1, tb);
    BARRIER();
    RD_A(0, 1, a1);                  // for ph3
    MFMA16(0, 1, a0, b1);
    BARRIER();
    // ph3
    if (more) STAGE_B(0, 0, t2);
    BARRIER();
    MFMA16(1, 1, a1, b1);
    BARRIER();
    // ph4 — gate tile b (buf1)
    if (more) { STAGE_B(0, 1, t2); WAIT_VM4(); } else { WAIT_VM0(); }
    BARRIER();
    RD_A(1, 0, a0); RD_B(1, 1, b1);  // for ph5 (buf1; a0/b1 old values dead)
    MFMA16(1, 0, a1, b0);
    BARRIER();
    // ---- tile b = 2i+1 (buf1), quadrants (01)(00)(10)(11) ----
    // ph5
    if (more) STAGE_A(0, 0, t2);
    BARRIER();
    RD_B(1, 0, b0);                  // for ph6 (b0 old last used ph4)
    MFMA16(0, 1, a0, b1);
    BARRIER();
    // ph6
    if (more) STAGE_A(0, 1, t2);
    BARRIER();
    RD_A(1, 1, a1);                  // for ph7 (a1 old last used ph4)
    MFMA16(0, 0, a0, b0);
    BARRIER();
    // ph7
    if (more) STAGE_B(1, 0, t3);
    BARRIER();
    MFMA16(1, 0, a1, b0);
    BARRIER();
    // ph8 — gate next tile (buf0, t2)
    if (more) { STAGE_B(1, 1, t3); WAIT_VM4(); }
    BARRIER();
    if (more) { RD_A(0, 0, a0); RD_B(0, 0, b0); }  // for next-iter ph1
    MFMA16(1, 1, a1, b1);
    BARRIER();
  }

#pragma unroll
  for (int mi = 0; mi < 8; mi++)
#pragma unroll
    for (int ni = 0; ni < 4; ni++) {
      int row = row0 + wy * 128 + mi * 16 + quad * 4;
      int col = col0 + wx * 64 + ni * 16 + l16;
      float* cp = C + (size_t)row * N + col;
#pragma unroll
      for (int r = 0; r < 4; r++) cp[(size_t)r * N] = acc[mi][ni][r];
    }
}

// ---------------- RMSNorm + RoPE for Q and K heads (Q pre-scaled by 1/sqrt(HD)) ----------------
__global__ void normrope(const float* __restrict__ qkv, const int* __restrict__ pos,
                         const float* __restrict__ qw, const float* __restrict__ kw,
                         u16* __restrict__ Qo, u16* __restrict__ Ko) {
  const int hh = blockIdx.x;
  const int t = blockIdx.y * 4 + (threadIdx.x >> 6);
  const int lane = threadIdx.x & 63;
  const bool isQ = hh < NQ;
  const int col = isQ ? hh * HD : HIDDEN + (hh - NQ) * HD;
  const float* src = qkv + (size_t)t * QKV_N + col;
  float x1 = src[lane], x2 = src[lane + 64];
  float ss = x1 * x1 + x2 * x2;
  for (int m = 1; m < 64; m <<= 1) ss += __shfl_xor(ss, m);
  float inv = rsqrtf(ss * (1.0f / 128.0f) + 1e-6f);
  const float* w = isQ ? qw : kw;
  x1 *= inv * w[lane];
  x2 *= inv * w[lane + 64];
  float p = (float)pos[t];
  float freq = expf((float)lane * -0.2158673525f);
  float a = p * freq;
  float sn = sinf(a), cs = cosf(a);
  float o1 = x1 * cs - x2 * sn;
  float o2 = x2 * cs + x1 * sn;
  const float osc = isQ ? 0.08838834764831845f : 1.0f;  // fold 1/sqrt(128) into Q
  u16* dst = isQ ? (Qo + (size_t)t * (NQ * HD) + hh * HD)
                 : (Ko + (size_t)t * (NKV * HD) + (hh - NQ) * HD);
  dst[lane] = f2bf(o1 * osc);
  dst[lane + 64] = f2bf(o2 * osc);
}

// ---------------- V: fp32 [t][5120+vh*128+d] -> bf16 vT[vh][d][t] ----------------
__global__ void vtrans(const float* __restrict__ qkv, u16* __restrict__ vT) {
  __shared__ float s[128][65];
  int tb = blockIdx.x;   // 0..31 (64-token block)
  int vh = blockIdx.y;   // 0..7
  int tid = threadIdx.x; // 256
  for (int i = 0; i < 32; i++) {
    int e = i * 256 + tid;
    int tl = e >> 7;
    int d = e & 127;
    s[d][tl] = qkv[(size_t)(tb * 64 + tl) * QKV_N + 5120 + vh * 128 + d];
  }
  __syncthreads();
  for (int i = 0; i < 32; i++) {
    int e = i * 256 + tid;
    int d = e >> 6;
    int tl = e & 63;
    vT[(size_t)vh * (HD * NTOK) + (size_t)d * NTOK + tb * 64 + tl] = f2bf(s[d][tl]);
  }
}

// ---------------- flash attention v3: 32x32 MFMA, in-register softmax, merged q-tile pair ----
__global__ __launch_bounds__(512, 2) void flash3(const u16* __restrict__ Q,
                                                 const u16* __restrict__ K,
                                                 const u16* __restrict__ V,
                                                 u16* __restrict__ O) {
  __shared__ u16 sK[64 * 136];
  __shared__ u16 sV[128 * 72];
  const int lid = blockIdx.x;
  const int kvh = lid & 7;
  const int head = kvh * 4 + ((lid >> 3) & 3);
  const int p = lid >> 5;
  const int tid = threadIdx.x;
  const int wave = tid >> 6, lane = tid & 63;
  const int l32 = lane & 31, h = lane >> 5;
  const int tileq = (wave < 4) ? p : (15 - p);
  const int qrow0 = tileq * 128 + (wave & 3) * 32;
  const u16* Vh = V + (size_t)kvh * (HD * NTOK);

  bf16x8 qf[8];
  const u16* qbase = Q + (size_t)(qrow0 + l32) * (NQ * HD) + head * HD + h * 8;
#pragma unroll
  for (int ks = 0; ks < 8; ks++)
    qf[ks] = *(const bf16x8*)(const void*)(qbase + ks * 16);

  f32x16 accO[4] = {};
  float l_loc = 0.f;
  const int nU = 32 - 2 * p;
  const int rk0 = tid >> 4, ck0 = tid & 15;
  const int rv0 = tid >> 3, cv0 = tid & 7;
  const u16* Kr = K + (size_t)kvh * HD + ck0 * 8;
  const u16* Vr = Vh + (size_t)rv0 * NTOK + cv0 * 8;
  const u16* Vr2 = Vh + (size_t)(rv0 + 64) * NTOK + cv0 * 8;

  u16x8 k0 = *(const u16x8*)(const void*)(Kr + (size_t)rk0 * (NKV * HD));
  u16x8 k1 = *(const u16x8*)(const void*)(Kr + (size_t)(rk0 + 32) * (NKV * HD));
  u16x8 v0 = *(const u16x8*)(const void*)(Vr);
  u16x8 v1 = *(const u16x8*)(const void*)(Vr2);

  for (int kb = 0; kb < nU; kb++) {
    __syncthreads();
    *(u16x8*)(void*)(sK + rk0 * 136 + ck0 * 8) = k0;
    *(u16x8*)(void*)(sK + (rk0 + 32) * 136 + ck0 * 8) = k1;
    *(u16x8*)(void*)(sV + rv0 * 72 + cv0 * 8) = v0;
    *(u16x8*)(void*)(sV + (rv0 + 64) * 72 + cv0 * 8) = v1;
    __syncthreads();
    if (kb + 1 < nU) {
      const size_t koff = (size_t)((kb + 1) * 64) * (NKV * HD);
      k0 = *(const u16x8*)(const void*)(Kr + koff + (size_t)rk0 * (NKV * HD));
      k1 = *(const u16x8*)(const void*)(Kr + koff + (size_t)(rk0 + 32) * (NKV * HD));
      v0 = *(const u16x8*)(const void*)(Vr + (kb + 1) * 64);
      v1 = *(const u16x8*)(const void*)(Vr2 + (kb + 1) * 64);
    }
    const int t0 = kb * 64;
    if (t0 > qrow0 + 31) continue;
    const bool act1 = (t0 + 32 <= qrow0 + 31);

    f32x16 s0 = {}, s1 = {};
#pragma unroll
    for (int ks = 0; ks < 8; ks++) {
      bf16x8 kf0 = *(const bf16x8*)(const void*)(sK + l32 * 136 + ks * 16 + h * 8);
      s0 = __builtin_amdgcn_mfma_f32_32x32x16_bf16(kf0, qf[ks], s0, 0, 0, 0);
    }
    if (act1) {
#pragma unroll
      for (int ks = 0; ks < 8; ks++) {
        bf16x8 kf1 = *(const bf16x8*)(const void*)(sK + (32 + l32) * 136 + ks * 16 + h * 8);
        s1 = __builtin_amdgcn_mfma_f32_32x32x16_bf16(kf1, qf[ks], s1, 0, 0, 0);
      }
    }

    auto process = [&](const f32x16& sv_, int tb) {
      float pr[16];
      const int tbase = t0 + tb * 32;
      const int qg = qrow0 + l32;
      if (tbase + 31 <= qrow0) {
#pragma unroll
        for (int r = 0; r < 16; r++) { float e = __expf(sv_[r]); pr[r] = e; l_loc += e; }
      } else {
#pragma unroll
        for (int r = 0; r < 16; r++) {
          const int tok = tbase + (r & 3) + 8 * (r >> 2) + 4 * h;
          float e = (tok <= qg) ? __expf(sv_[r]) : 0.f;
          pr[r] = e; l_loc += e;
        }
      }
#pragma unroll
      for (int u = 0; u < 2; u++) {
        uint32_t A0, A1, B0, B1;
        asm("v_cvt_pk_bf16_f32 %0, %1, %2" : "=v"(A0) : "v"(pr[u * 8 + 0]), "v"(pr[u * 8 + 1]));
        asm("v_cvt_pk_bf16_f32 %0, %1, %2" : "=v"(A1) : "v"(pr[u * 8 + 2]), "v"(pr[u * 8 + 3]));
        asm("v_cvt_pk_bf16_f32 %0, %1, %2" : "=v"(B0) : "v"(pr[u * 8 + 4]), "v"(pr[u * 8 + 5]));
        asm("v_cvt_pk_bf16_f32 %0, %1, %2" : "=v"(B1) : "v"(pr[u * 8 + 6]), "v"(pr[u * 8 + 7]));
#if __has_builtin(__builtin_amdgcn_permlane32_swap)
        i32x2 r02 = __builtin_amdgcn_permlane32_swap((int)A0, (int)B0, false, false);
        i32x2 r13 = __builtin_amdgcn_permlane32_swap((int)A1, (int)B1, false, false);
        const uint32_t w0 = (uint32_t)r02.x, w2 = (uint32_t)r02.y;
        const uint32_t w1 = (uint32_t)r13.x, w3 = (uint32_t)r13.y;
#else
        const uint32_t A0x = (uint32_t)__shfl_xor((int)A0, 32);
        const uint32_t A1x = (uint32_t)__shfl_xor((int)A1, 32);
        const uint32_t B0x = (uint32_t)__shfl_xor((int)B0, 32);
        const uint32_t B1x = (uint32_t)__shfl_xor((int)B1, 32);
        const uint32_t w0 = h ? B0x : A0;
        const uint32_t w1 = h ? B1x : A1;
        const uint32_t w2 = h ? B0 : A0x;
        const uint32_t w3 = h ? B1 : A1x;
#endif
        union { u32x4 w; bf16x8 v; } pf;
        pf.w = (u32x4){w0, w1, w2, w3};
#pragma unroll
        for (int db = 0; db < 4; db++) {
          bf16x8 vf = *(const bf16x8*)(const void*)(sV + (db * 32 + l32) * 72 + tb * 32 + u * 16 + h * 8);
          accO[db] = __builtin_amdgcn_mfma_f32_32x32x16_bf16(vf, pf.v, accO[db], 0, 0, 0);
        }
      }
    };
    process(s0, 0);
    if (act1) process(s1, 1);
  }

  l_loc += __shfl_xor(l_loc, 32);
  const float inv = 1.0f / l_loc;
  u16* ob = O + (size_t)(qrow0 + l32) * (NQ * HD) + head * HD;
#pragma unroll
  for (int db = 0; db < 4; db++)
#pragma unroll
    for (int g = 0; g < 4; g++) {
      u16x4 o4;
#pragma unroll
      for (int j = 0; j < 4; j++) o4[j] = f2bf(accO[db][4 * g + j] * inv);
      *(u16x4*)(void*)(ob + db * 32 + g * 8 + h * 4) = o4;
    }
}

extern "C" void kernel_launch(void* const* d_in, const int* in_sizes, int n_in,
                              void* d_out, int out_size, void* d_ws, size_t ws_size,
                              hipStream_t stream) {
  const float* hidden = (const float*)d_in[0];
  const int* positions = (const int*)d_in[1];
  const float* Wq = (const float*)d_in[2];
  const float* Wk = (const float*)d_in[3];
  const float* Wv = (const float*)d_in[4];
  const float* Wo = (const float*)d_in[5];
  const float* qw = (const float*)d_in[6];
  const float* kw = (const float*)d_in[7];
  char* ws = (char*)d_ws;
  u16* hid_bf  = (u16*)(ws);                    // 16 MB
  u16* WqkvT   = (u16*)(ws + 16777216);         // 48 MB
  u16* WoT     = (u16*)(ws + 67108864);         // 32 MB
  float* qkvf  = (float*)(ws + 100663296);      // 48 MB
  u16* Qn      = (u16*)(ws + 150994944);        // 16 MB
  u16* Kn      = (u16*)(ws + 167772160);        //  4 MB
  u16* Vt      = (u16*)(ws + 171966464);        //  4 MB
  u16* AO      = (u16*)(ws + 176160768);        // 16 MB
  float* outp  = (float*)d_out;

  cvt_hidden<<<NTOK * HIDDEN / 4 / 256, 256, 0, stream>>>(hidden, hid_bf, NTOK * HIDDEN / 4);
  transpose_cvt<<<dim3(64, 64), 256, 0, stream>>>(Wq, WqkvT, 4096, 4096);
  transpose_cvt<<<dim3(16, 64), 256, 0, stream>>>(Wk, WqkvT + (size_t)4096 * 4096, 4096, 1024);
  transpose_cvt<<<dim3(16, 64), 256, 0, stream>>>(Wv, WqkvT + (size_t)5120 * 4096, 4096, 1024);
  transpose_cvt<<<dim3(64, 64), 256, 0, stream>>>(Wo, WoT, 4096, 4096);
  gemm256<<<dim3(24, 8), 512, 0, stream>>>(hid_bf, WqkvT, qkvf, 2048, 6144, 4096);
  normrope<<<dim3(40, 512), 256, 0, stream>>>(qkvf, positions, qw, kw, Qn, Kn);
  vtrans<<<dim3(32, 8), 256, 0, stream>>>(qkvf, Vt);
  flash3<<<dim3(256), 512, 0, stream>>>(Qn, Kn, Vt, AO);
  gemm256<<<dim3(16, 8), 512, 0, stream>>>(AO, WoT, outp, 2048, 4096, 4096);
}

// Round 4
// 471.038 us; speedup vs baseline: 1.4378x; 1.4378x over previous
//
#include <hip/hip_runtime.h>
#include <stdint.h>

typedef unsigned short u16;
typedef __bf16 bf16_t;
typedef bf16_t bf16x8 __attribute__((ext_vector_type(8)));
typedef float f32x4 __attribute__((ext_vector_type(4)));
typedef float f32x16 __attribute__((ext_vector_type(16)));
typedef u16 u16x4 __attribute__((ext_vector_type(4)));
typedef u16 u16x8 __attribute__((ext_vector_type(8)));
typedef uint32_t u32x4 __attribute__((ext_vector_type(4)));
typedef int i32x2 __attribute__((ext_vector_type(2)));

#define HIDDEN 4096
#define NTOK 2048
#define NQ 32
#define NKV 8
#define HD 128
#define QKV_N 6144

#define AS1 __attribute__((address_space(1)))
#define AS3 __attribute__((address_space(3)))

__device__ __forceinline__ u16 f2bf(float f) {
  union { float f; uint32_t u; } v; v.f = f;
  uint32_t u = v.u;
  return (u16)((u + 0x7fffu + ((u >> 16) & 1u)) >> 16);
}

// ---------------- hidden fp32 -> bf16 ----------------
__global__ void cvt_hidden(const float* __restrict__ src, u16* __restrict__ dst, int n4) {
  int i = blockIdx.x * blockDim.x + threadIdx.x;
  if (i >= n4) return;
  float4 v = ((const float4*)src)[i];
  u16x4 o;
  o[0] = f2bf(v.x); o[1] = f2bf(v.y); o[2] = f2bf(v.z); o[3] = f2bf(v.w);
  ((u16x4*)dst)[i] = o;
}

// ------------- vectorized 64x64 transpose tile: dst[c][r] = bf16(src[r][c]) -------------
// float4 loads (16 B/lane), u16x4 transposed stores (8 B/lane). LDS pad 65 -> 2-way
// bank aliasing on both phases (free on CDNA4).
__device__ __forceinline__ void ttile64(const float* __restrict__ src, size_t sstride, int scol,
                                        u16* __restrict__ dst, size_t dstride,
                                        int r0, int c0, int tid, float (*tile)[65]) {
#pragma unroll
  for (int pass = 0; pass < 4; pass++) {
    int idx = pass * 256 + tid;
    int r = idx >> 4, c4 = idx & 15;
    float4 v = *(const float4*)(src + (size_t)(r0 + r) * sstride + scol + c4 * 4);
    tile[r][c4 * 4 + 0] = v.x;
    tile[r][c4 * 4 + 1] = v.y;
    tile[r][c4 * 4 + 2] = v.z;
    tile[r][c4 * 4 + 3] = v.w;
  }
  __syncthreads();
#pragma unroll
  for (int pass = 0; pass < 4; pass++) {
    int idx = pass * 256 + tid;
    int c = idx >> 4, rq = (idx & 15) * 4;
    u16x4 o;
#pragma unroll
    for (int j = 0; j < 4; j++) o[j] = f2bf(tile[rq + j][c]);
    *(u16x4*)(dst + (size_t)(c0 + c) * dstride + r0 + rq) = o;
  }
}

// one launch for Wq|Wk|Wv -> WqkvT (rows n=0..6143, stride 4096)
__global__ void prep_qkvT(const float* __restrict__ Wq, const float* __restrict__ Wk,
                          const float* __restrict__ Wv, u16* __restrict__ dst) {
  __shared__ float tile[64][65];
  const int c0 = blockIdx.x * 64, r0 = blockIdx.y * 64;
  const float* src; int scol; size_t sstride;
  if (c0 < 4096)      { src = Wq; scol = c0;        sstride = 4096; }
  else if (c0 < 5120) { src = Wk; scol = c0 - 4096; sstride = 1024; }
  else                { src = Wv; scol = c0 - 5120; sstride = 1024; }
  ttile64(src, sstride, scol, dst, 4096, r0, c0, threadIdx.x, tile);
}

__global__ void prep_woT(const float* __restrict__ Wo, u16* __restrict__ dst) {
  __shared__ float tile[64][65];
  const int c0 = blockIdx.x * 64, r0 = blockIdx.y * 64;
  ttile64(Wo, 4096, c0, dst, 4096, r0, c0, threadIdx.x, tile);
}

// ---------------- GEMM: C[M][N] = A[M][K] * B[N][K]^T  (bf16 in, fp32 out) ----------------
// BK=64, XOR-swizzled LDS chunk layout, global_load_lds width-16 staging, 16x16x32 MFMA,
// 64x64 per wave. Fused epilogue: blocks with col0 >= 5120 (V region of the QKV GEMM)
// write bf16 V^T [vh][d][t] directly instead of fp32 C.
__global__ __launch_bounds__(256, 3) void gemm_bt(const u16* __restrict__ A,
                                                  const u16* __restrict__ B,
                                                  float* __restrict__ C,
                                                  u16* __restrict__ vT,
                                                  int M, int N, int K) {
  __shared__ u16 sA[128 * 64];
  __shared__ u16 sB[128 * 64];
  const int tid = threadIdx.x;
  const int wave = tid >> 6, lane = tid & 63;
  const int quad = lane >> 4, l16 = lane & 15;
  const int wy = wave >> 1, wx = wave & 1;
  const int row0 = blockIdx.y * 128, col0 = blockIdx.x * 128;
  f32x4 acc[4][4] = {};
  const int lr = lane >> 3;
  const int sc = (lane & 7) ^ lr;
  const u16* gA = A + (size_t)(row0 + wave * 32 + lr) * K + sc * 8;
  const u16* gB = B + (size_t)(col0 + wave * 32 + lr) * K + sc * 8;
  u16* lA = sA + wave * 32 * 64;
  u16* lB = sB + wave * 32 * 64;
  const int swz = l16 & 7;
  for (int k0 = 0; k0 < K; k0 += 64) {
    for (int j = 0; j < 4; j++) {
      __builtin_amdgcn_global_load_lds(
          (AS1 void*)(void*)(gA + k0 + (size_t)(j * 8) * K),
          (AS3 void*)(void*)(lA + j * 8 * 64), 16, 0, 0);
      __builtin_amdgcn_global_load_lds(
          (AS1 void*)(void*)(gB + k0 + (size_t)(j * 8) * K),
          (AS3 void*)(void*)(lB + j * 8 * 64), 16, 0, 0);
    }
    __syncthreads();
    bf16x8 af[2][4], bfr[2][4];
    for (int s = 0; s < 2; s++)
      for (int mi = 0; mi < 4; mi++) {
        const int c = ((s * 4 + quad) ^ swz) * 8;
        af[s][mi] = *(const bf16x8*)(const void*)(sA + (wy * 64 + mi * 16 + l16) * 64 + c);
        bfr[s][mi] = *(const bf16x8*)(const void*)(sB + (wx * 64 + mi * 16 + l16) * 64 + c);
      }
    for (int s = 0; s < 2; s++)
      for (int mi = 0; mi < 4; mi++)
        for (int ni = 0; ni < 4; ni++)
          acc[mi][ni] = __builtin_amdgcn_mfma_f32_16x16x32_bf16(af[s][mi], bfr[s][ni], acc[mi][ni], 0, 0, 0);
    __syncthreads();
  }
  if (vT != nullptr && col0 >= 5120) {
    // V region: write vT[vh][d][t] = bf16(C[t][5120 + vh*128 + d]); t contiguous per lane.
#pragma unroll
    for (int mi = 0; mi < 4; mi++)
#pragma unroll
      for (int ni = 0; ni < 4; ni++) {
        int row = row0 + wy * 64 + mi * 16 + quad * 4;           // t
        int vcol = col0 + wx * 64 + ni * 16 + l16 - 5120;         // vh*128 + d
        u16x4 o;
#pragma unroll
        for (int r = 0; r < 4; r++) o[r] = f2bf(acc[mi][ni][r]);
        *(u16x4*)(vT + (size_t)vcol * NTOK + row) = o;
      }
  } else {
#pragma unroll
    for (int mi = 0; mi < 4; mi++)
#pragma unroll
      for (int ni = 0; ni < 4; ni++) {
        int row = row0 + wy * 64 + mi * 16 + quad * 4;
        int col = col0 + wx * 64 + ni * 16 + l16;
        float* cp = C + (size_t)row * N + col;
#pragma unroll
        for (int r = 0; r < 4; r++) cp[(size_t)r * N] = acc[mi][ni][r];
      }
  }
}

// ---------------- RMSNorm + RoPE for Q and K heads (Q pre-scaled by 1/sqrt(HD)) ----------------
__global__ void normrope(const float* __restrict__ qkv, const int* __restrict__ pos,
                         const float* __restrict__ qw, const float* __restrict__ kw,
                         u16* __restrict__ Qo, u16* __restrict__ Ko) {
  const int hh = blockIdx.x;
  const int t = blockIdx.y * 4 + (threadIdx.x >> 6);
  const int lane = threadIdx.x & 63;
  const bool isQ = hh < NQ;
  const int col = isQ ? hh * HD : HIDDEN + (hh - NQ) * HD;
  const float* src = qkv + (size_t)t * QKV_N + col;
  float x1 = src[lane], x2 = src[lane + 64];
  float ss = x1 * x1 + x2 * x2;
  for (int m = 1; m < 64; m <<= 1) ss += __shfl_xor(ss, m);
  float inv = rsqrtf(ss * (1.0f / 128.0f) + 1e-6f);
  const float* w = isQ ? qw : kw;
  x1 *= inv * w[lane];
  x2 *= inv * w[lane + 64];
  float p = (float)pos[t];
  float freq = expf((float)lane * -0.2158673525f);
  float a = p * freq;
  float sn = sinf(a), cs = cosf(a);
  float o1 = x1 * cs - x2 * sn;
  float o2 = x2 * cs + x1 * sn;
  const float osc = isQ ? 0.08838834764831845f : 1.0f;  // fold 1/sqrt(128) into Q
  u16* dst = isQ ? (Qo + (size_t)t * (NQ * HD) + hh * HD)
                 : (Ko + (size_t)t * (NKV * HD) + (hh - NQ) * HD);
  dst[lane] = f2bf(o1 * osc);
  dst[lane + 64] = f2bf(o2 * osc);
}

// ---------------- flash attention v3: 32x32 MFMA, in-register softmax, merged q-tile pair ----
__global__ __launch_bounds__(512, 2) void flash3(const u16* __restrict__ Q,
                                                 const u16* __restrict__ K,
                                                 const u16* __restrict__ V,
                                                 u16* __restrict__ O) {
  __shared__ u16 sK[64 * 136];
  __shared__ u16 sV[128 * 72];
  const int lid = blockIdx.x;
  const int kvh = lid & 7;
  const int head = kvh * 4 + ((lid >> 3) & 3);
  const int p = lid >> 5;
  const int tid = threadIdx.x;
  const int wave = tid >> 6, lane = tid & 63;
  const int l32 = lane & 31, h = lane >> 5;
  const int tileq = (wave < 4) ? p : (15 - p);
  const int qrow0 = tileq * 128 + (wave & 3) * 32;
  const u16* Vh = V + (size_t)kvh * (HD * NTOK);

  bf16x8 qf[8];
  const u16* qbase = Q + (size_t)(qrow0 + l32) * (NQ * HD) + head * HD + h * 8;
#pragma unroll
  for (int ks = 0; ks < 8; ks++)
    qf[ks] = *(const bf16x8*)(const void*)(qbase + ks * 16);

  f32x16 accO[4] = {};
  float l_loc = 0.f;
  const int nU = 32 - 2 * p;
  const int rk0 = tid >> 4, ck0 = tid & 15;
  const int rv0 = tid >> 3, cv0 = tid & 7;
  const u16* Kr = K + (size_t)kvh * HD + ck0 * 8;
  const u16* Vr = Vh + (size_t)rv0 * NTOK + cv0 * 8;
  const u16* Vr2 = Vh + (size_t)(rv0 + 64) * NTOK + cv0 * 8;

  u16x8 k0 = *(const u16x8*)(const void*)(Kr + (size_t)rk0 * (NKV * HD));
  u16x8 k1 = *(const u16x8*)(const void*)(Kr + (size_t)(rk0 + 32) * (NKV * HD));
  u16x8 v0 = *(const u16x8*)(const void*)(Vr);
  u16x8 v1 = *(const u16x8*)(const void*)(Vr2);

  for (int kb = 0; kb < nU; kb++) {
    __syncthreads();
    *(u16x8*)(void*)(sK + rk0 * 136 + ck0 * 8) = k0;
    *(u16x8*)(void*)(sK + (rk0 + 32) * 136 + ck0 * 8) = k1;
    *(u16x8*)(void*)(sV + rv0 * 72 + cv0 * 8) = v0;
    *(u16x8*)(void*)(sV + (rv0 + 64) * 72 + cv0 * 8) = v1;
    __syncthreads();
    if (kb + 1 < nU) {
      const size_t koff = (size_t)((kb + 1) * 64) * (NKV * HD);
      k0 = *(const u16x8*)(const void*)(Kr + koff + (size_t)rk0 * (NKV * HD));
      k1 = *(const u16x8*)(const void*)(Kr + koff + (size_t)(rk0 + 32) * (NKV * HD));
      v0 = *(const u16x8*)(const void*)(Vr + (kb + 1) * 64);
      v1 = *(const u16x8*)(const void*)(Vr2 + (kb + 1) * 64);
    }
    const int t0 = kb * 64;
    if (t0 > qrow0 + 31) continue;
    const bool act1 = (t0 + 32 <= qrow0 + 31);

    f32x16 s0 = {}, s1 = {};
#pragma unroll
    for (int ks = 0; ks < 8; ks++) {
      bf16x8 kf0 = *(const bf16x8*)(const void*)(sK + l32 * 136 + ks * 16 + h * 8);
      s0 = __builtin_amdgcn_mfma_f32_32x32x16_bf16(kf0, qf[ks], s0, 0, 0, 0);
    }
    if (act1) {
#pragma unroll
      for (int ks = 0; ks < 8; ks++) {
        bf16x8 kf1 = *(const bf16x8*)(const void*)(sK + (32 + l32) * 136 + ks * 16 + h * 8);
        s1 = __builtin_amdgcn_mfma_f32_32x32x16_bf16(kf1, qf[ks], s1, 0, 0, 0);
      }
    }

    auto process = [&](const f32x16& sv_, int tb) {
      float pr[16];
      const int tbase = t0 + tb * 32;
      const int qg = qrow0 + l32;
      if (tbase + 31 <= qrow0) {
#pragma unroll
        for (int r = 0; r < 16; r++) { float e = __expf(sv_[r]); pr[r] = e; l_loc += e; }
      } else {
#pragma unroll
        for (int r = 0; r < 16; r++) {
          const int tok = tbase + (r & 3) + 8 * (r >> 2) + 4 * h;
          float e = (tok <= qg) ? __expf(sv_[r]) : 0.f;
          pr[r] = e; l_loc += e;
        }
      }
#pragma unroll
      for (int u = 0; u < 2; u++) {
        uint32_t A0, A1, B0, B1;
        asm("v_cvt_pk_bf16_f32 %0, %1, %2" : "=v"(A0) : "v"(pr[u * 8 + 0]), "v"(pr[u * 8 + 1]));
        asm("v_cvt_pk_bf16_f32 %0, %1, %2" : "=v"(A1) : "v"(pr[u * 8 + 2]), "v"(pr[u * 8 + 3]));
        asm("v_cvt_pk_bf16_f32 %0, %1, %2" : "=v"(B0) : "v"(pr[u * 8 + 4]), "v"(pr[u * 8 + 5]));
        asm("v_cvt_pk_bf16_f32 %0, %1, %2" : "=v"(B1) : "v"(pr[u * 8 + 6]), "v"(pr[u * 8 + 7]));
#if __has_builtin(__builtin_amdgcn_permlane32_swap)
        i32x2 r02 = __builtin_amdgcn_permlane32_swap((int)A0, (int)B0, false, false);
        i32x2 r13 = __builtin_amdgcn_permlane32_swap((int)A1, (int)B1, false, false);
        const uint32_t w0 = (uint32_t)r02.x, w2 = (uint32_t)r02.y;
        const uint32_t w1 = (uint32_t)r13.x, w3 = (uint32_t)r13.y;
#else
        const uint32_t A0x = (uint32_t)__shfl_xor((int)A0, 32);
        const uint32_t A1x = (uint32_t)__shfl_xor((int)A1, 32);
        const uint32_t B0x = (uint32_t)__shfl_xor((int)B0, 32);
        const uint32_t B1x = (uint32_t)__shfl_xor((int)B1, 32);
        const uint32_t w0 = h ? B0x : A0;
        const uint32_t w1 = h ? B1x : A1;
        const uint32_t w2 = h ? B0 : A0x;
        const uint32_t w3 = h ? B1 : A1x;
#endif
        union { u32x4 w; bf16x8 v; } pf;
        pf.w = (u32x4){w0, w1, w2, w3};
#pragma unroll
        for (int db = 0; db < 4; db++) {
          bf16x8 vf = *(const bf16x8*)(const void*)(sV + (db * 32 + l32) * 72 + tb * 32 + u * 16 + h * 8);
          accO[db] = __builtin_amdgcn_mfma_f32_32x32x16_bf16(vf, pf.v, accO[db], 0, 0, 0);
        }
      }
    };
    process(s0, 0);
    if (act1) process(s1, 1);
  }

  l_loc += __shfl_xor(l_loc, 32);
  const float inv = 1.0f / l_loc;
  u16* ob = O + (size_t)(qrow0 + l32) * (NQ * HD) + head * HD;
#pragma unroll
  for (int db = 0; db < 4; db++)
#pragma unroll
    for (int g = 0; g < 4; g++) {
      u16x4 o4;
#pragma unroll
      for (int j = 0; j < 4; j++) o4[j] = f2bf(accO[db][4 * g + j] * inv);
      *(u16x4*)(void*)(ob + db * 32 + g * 8 + h * 4) = o4;
    }
}

extern "C" void kernel_launch(void* const* d_in, const int* in_sizes, int n_in,
                              void* d_out, int out_size, void* d_ws, size_t ws_size,
                              hipStream_t stream) {
  const float* hidden = (const float*)d_in[0];
  const int* positions = (const int*)d_in[1];
  const float* Wq = (const float*)d_in[2];
  const float* Wk = (const float*)d_in[3];
  const float* Wv = (const float*)d_in[4];
  const float* Wo = (const float*)d_in[5];
  const float* qw = (const float*)d_in[6];
  const float* kw = (const float*)d_in[7];
  char* ws = (char*)d_ws;
  u16* hid_bf  = (u16*)(ws);                    // 16 MB
  u16* WqkvT   = (u16*)(ws + 16777216);         // 48 MB
  u16* WoT     = (u16*)(ws + 67108864);         // 32 MB
  float* qkvf  = (float*)(ws + 100663296);      // 48 MB
  u16* Qn      = (u16*)(ws + 150994944);        // 16 MB
  u16* Kn      = (u16*)(ws + 167772160);        //  4 MB
  u16* Vt      = (u16*)(ws + 171966464);        //  4 MB
  u16* AO      = (u16*)(ws + 176160768);        // 16 MB
  float* outp  = (float*)d_out;

  cvt_hidden<<<NTOK * HIDDEN / 4 / 256, 256, 0, stream>>>(hidden, hid_bf, NTOK * HIDDEN / 4);
  prep_qkvT<<<dim3(96, 64), 256, 0, stream>>>(Wq, Wk, Wv, WqkvT);
  prep_woT<<<dim3(64, 64), 256, 0, stream>>>(Wo, WoT);
  gemm_bt<<<dim3(48, 16), 256, 0, stream>>>(hid_bf, WqkvT, qkvf, Vt, 2048, 6144, 4096);
  normrope<<<dim3(40, 512), 256, 0, stream>>>(qkvf, positions, qw, kw, Qn, Kn);
  flash3<<<dim3(256), 512, 0, stream>>>(Qn, Kn, Vt, AO);
  gemm_bt<<<dim3(32, 16), 256, 0, stream>>>(AO, WoT, outp, nullptr, 2048, 4096, 4096);
}